// Round 3
// baseline (1229.236 us; speedup 1.0000x reference)
//
#include <hip/hip_runtime.h>
#include <hip/hip_bf16.h>
#include <stdint.h>

typedef __attribute__((ext_vector_type(4)))  float    f32x4;
typedef __attribute__((ext_vector_type(16))) float    f32x16;
typedef __attribute__((ext_vector_type(8)))  short    short8;
typedef __attribute__((ext_vector_type(4)))  uint32_t u32x4;

#define NB 256
#define NG 2000
#define NH 256
#define NT_PER_B 63                  /* ceil(2000/32) */
#define TOTAL_TILES (NT_PER_B * NB)  /* 16128 */

// pack two f32 -> two bf16 (round-half-up) in one u32 via v_perm
__device__ __forceinline__ uint32_t pack2_bf16(float lo, float hi) {
    uint32_t ulo = __builtin_bit_cast(uint32_t, lo) + 0x8000u;
    uint32_t uhi = __builtin_bit_cast(uint32_t, hi) + 0x8000u;
    return __builtin_amdgcn_perm(uhi, ulo, 0x07060302u);
}

// tanh(x) = 1 - 2/(1+e^{2x}); saturates correctly at +-inf
__device__ __forceinline__ float tanh_fast(float x) {
    float e = __expf(2.0f * x);
    return 1.0f - __fdividef(2.0f, 1.0f + e);
}

// qb[b][k] = dot(query[b], Wq[k]) + bq[k] + be[k]
__global__ __launch_bounds__(256) void qb_kernel(
    const float* __restrict__ query, const float* __restrict__ Wq,
    const float* __restrict__ bq, const float* __restrict__ be,
    float* __restrict__ qb)
{
    __shared__ __align__(16) float qrow[512];
    const int b = blockIdx.x;
    const int t = threadIdx.x;
    qrow[t]       = query[b * 512 + t];
    qrow[t + 256] = query[b * 512 + t + 256];
    __syncthreads();
    const float* wrow = Wq + (size_t)t * 512;
    float acc = 0.0f;
#pragma unroll 8
    for (int j = 0; j < 128; ++j) {
        f32x4 w = *(const f32x4*)(wrow + j * 4);
        f32x4 q = *(const f32x4*)(qrow + j * 4);
        acc = fmaf(w[0], q[0], acc);
        acc = fmaf(w[1], q[1], acc);
        acc = fmaf(w[2], q[2], acc);
        acc = fmaf(w[3], q[3], acc);
    }
    qb[b * 256 + t] = acc + bq[t] + be[t];
}

// Main: e = ref @ We.T (bf16 MFMA), tanh(qb + e) . v  -> scores [B][G]
__global__ __launch_bounds__(512, 2) void attn_kernel(
    const float* __restrict__ ref, const float* __restrict__ We,
    const float* __restrict__ vvec, const float* __restrict__ qb,
    float* __restrict__ out)
{
    extern __shared__ char lds[];   // 131072 B: We as bf16 [256 rows][512 B], XOR-swizzled
    const int tid = threadIdx.x;

    // ---- stage We (f32 global -> bf16 LDS, swizzle byte ^= (row&7)<<4) ----
    // Each thread owns half a row: 128 f32 -> 256 B of bf16, in 16 iters of
    // 8 floats -> one 16 B write at stride 16 (FIX: was 8 iters / stride 32,
    // leaving half of LDS uninitialized -> NaN).
    {
        const int r = tid >> 1;       // row 0..255 (= output feature n)
        const int h = tid & 1;        // which half of the row
        const float* src = We + (size_t)r * 256 + h * 128;
        const uint32_t swz = (uint32_t)((r & 7) << 4);
#pragma unroll
        for (int i = 0; i < 16; ++i) {
            f32x4 w0 = *(const f32x4*)(src + i * 8);
            f32x4 w1 = *(const f32x4*)(src + i * 8 + 4);
            u32x4 p;
            p[0] = pack2_bf16(w0[0], w0[1]);
            p[1] = pack2_bf16(w0[2], w0[3]);
            p[2] = pack2_bf16(w1[0], w1[1]);
            p[3] = pack2_bf16(w1[2], w1[3]);
            const uint32_t cb = (uint32_t)(h * 256 + i * 16);
            *(u32x4*)(lds + r * 512 + (cb ^ swz)) = p;
        }
    }
    __syncthreads();

    const int lane = tid & 63;
    const int wid  = tid >> 6;
    const int l31  = lane & 31;
    const int lhi  = lane >> 5;           // k-group half

    const uint32_t bbase = (uint32_t)(l31 * 512);        // B-frag row base (n within tile)
    const uint32_t bswz  = (uint32_t)((l31 & 7) << 4);
    const int      bcol0 = lhi * 16;                     // byte offset of k-group

    // v[col] is tile-invariant: hoist (col = nt*32 + l31)
    float vreg[8];
#pragma unroll
    for (int nt = 0; nt < 8; ++nt) vreg[nt] = vvec[nt * 32 + l31];

    const int gw = blockIdx.x * 8 + wid;
    const int nw = gridDim.x * 8;

    for (int tile = gw; tile < TOTAL_TILES; tile += nw) {
        const int b  = tile / NT_PER_B;
        const int mt = tile - b * NT_PER_B;
        const int g0 = mt * 32;
        int gr = g0 + l31;
        if (gr > NG - 1) gr = NG - 1;     // clamp tail tile (rows not written)
        const float* ap = ref + ((size_t)(b * NG + gr)) * 256 + lhi * 8;

        f32x16 acc[8] = {};

        // 4-deep A prefetch pipeline (8 f32 per k-step per lane)
        f32x4 abuf[4][2];
#pragma unroll
        for (int p = 0; p < 4; ++p) {
            abuf[p][0] = *(const f32x4*)(ap + p * 16);
            abuf[p][1] = *(const f32x4*)(ap + p * 16 + 4);
        }
#pragma unroll
        for (int ks = 0; ks < 16; ++ks) {
            u32x4 aq;
            aq[0] = pack2_bf16(abuf[ks & 3][0][0], abuf[ks & 3][0][1]);
            aq[1] = pack2_bf16(abuf[ks & 3][0][2], abuf[ks & 3][0][3]);
            aq[2] = pack2_bf16(abuf[ks & 3][1][0], abuf[ks & 3][1][1]);
            aq[3] = pack2_bf16(abuf[ks & 3][1][2], abuf[ks & 3][1][3]);
            short8 afrag = __builtin_bit_cast(short8, aq);
            if (ks < 12) {
                abuf[ks & 3][0] = *(const f32x4*)(ap + (ks + 4) * 16);
                abuf[ks & 3][1] = *(const f32x4*)(ap + (ks + 4) * 16 + 4);
            }
            const uint32_t cb = ((uint32_t)(ks * 32 + bcol0)) ^ bswz;
#pragma unroll
            for (int nt = 0; nt < 8; ++nt) {
                short8 bfrag = *(const short8*)(lds + bbase + nt * 16384 + cb);
                acc[nt] = __builtin_amdgcn_mfma_f32_32x32x16_bf16(afrag, bfrag, acc[nt], 0, 0, 0);
            }
        }

        // ---- epilogue: tanh(acc + qb) . v, butterfly-reduce over 32 col-lanes ----
        float sums[16];
#pragma unroll
        for (int r = 0; r < 16; ++r) sums[r] = 0.0f;
        const float* qrow = qb + b * 256;
#pragma unroll
        for (int nt = 0; nt < 8; ++nt) {
            const float qv = qrow[nt * 32 + l31];
            const float vv = vreg[nt];
#pragma unroll
            for (int r = 0; r < 16; ++r) {
                sums[r] = fmaf(tanh_fast(acc[nt][r] + qv), vv, sums[r]);
            }
        }
#pragma unroll
        for (int r = 0; r < 16; ++r) {
            float s = sums[r];
            s += __shfl_xor(s, 1);
            s += __shfl_xor(s, 2);
            s += __shfl_xor(s, 4);
            s += __shfl_xor(s, 8);
            s += __shfl_xor(s, 16);
            sums[r] = s;
        }
        if (l31 == 0) {   // lanes 0 and 32 write 16 rows each
            float* orow = out + (size_t)b * NG;
#pragma unroll
            for (int r = 0; r < 16; ++r) {
                const int rr = (r & 3) + 8 * (r >> 2) + 4 * lhi;  // C/D row map (m74/m101)
                const int g = g0 + rr;
                if (g < NG) orow[g] = sums[r];
            }
        }
    }
}

extern "C" void kernel_launch(void* const* d_in, const int* in_sizes, int n_in,
                              void* d_out, int out_size, void* d_ws, size_t ws_size,
                              hipStream_t stream) {
    const float* query = (const float*)d_in[0];
    const float* ref   = (const float*)d_in[1];
    const float* Wq    = (const float*)d_in[2];
    const float* bq    = (const float*)d_in[3];
    const float* We    = (const float*)d_in[4];
    const float* be    = (const float*)d_in[5];
    const float* v     = (const float*)d_in[6];
    float* out = (float*)d_out;
    float* qb  = (float*)d_ws;   // 256*256 f32 = 256 KB scratch

    // Allow 128 KiB dynamic LDS. Unconditional (idempotent, non-stream,
    // capture-safe) -- no call-count-dependent behavior.
    (void)hipFuncSetAttribute((const void*)attn_kernel,
                              hipFuncAttributeMaxDynamicSharedMemorySize, 131072);

    qb_kernel<<<dim3(NB), dim3(256), 0, stream>>>(query, Wq, bq, be, qb);
    attn_kernel<<<dim3(256), dim3(512), 131072, stream>>>(ref, We, v, qb, out);
}

// Round 4
// 1218.099 us; speedup vs baseline: 1.0091x; 1.0091x over previous
//
#include <hip/hip_runtime.h>
#include <hip/hip_bf16.h>
#include <stdint.h>

typedef __attribute__((ext_vector_type(4)))  float    f32x4;
typedef __attribute__((ext_vector_type(16))) float    f32x16;
typedef __attribute__((ext_vector_type(8)))  short    short8;
typedef __attribute__((ext_vector_type(4)))  uint32_t u32x4;

#define NB 256
#define NG 2000
#define NH 256
#define NT_PER_B 63                  /* ceil(2000/32) */
#define TOTAL_TILES (NT_PER_B * NB)  /* 16128 */

// pack two f32 -> two bf16 (round-half-up) in one u32 via v_perm
__device__ __forceinline__ uint32_t pack2_bf16(float lo, float hi) {
    uint32_t ulo = __builtin_bit_cast(uint32_t, lo) + 0x8000u;
    uint32_t uhi = __builtin_bit_cast(uint32_t, hi) + 0x8000u;
    return __builtin_amdgcn_perm(uhi, ulo, 0x07060302u);
}

// tanh(x) = 1 - 2/(1+e^{2x}); saturates correctly at +-inf
__device__ __forceinline__ float tanh_fast(float x) {
    float e = __expf(2.0f * x);
    return 1.0f - __fdividef(2.0f, 1.0f + e);
}

// qb[b][k] = dot(query[b], Wq[k]) + bq[k] + be[k]
__global__ __launch_bounds__(256) void qb_kernel(
    const float* __restrict__ query, const float* __restrict__ Wq,
    const float* __restrict__ bq, const float* __restrict__ be,
    float* __restrict__ qb)
{
    __shared__ __align__(16) float qrow[512];
    const int b = blockIdx.x;
    const int t = threadIdx.x;
    qrow[t]       = query[b * 512 + t];
    qrow[t + 256] = query[b * 512 + t + 256];
    __syncthreads();
    const float* wrow = Wq + (size_t)t * 512;
    float acc = 0.0f;
#pragma unroll 8
    for (int j = 0; j < 128; ++j) {
        f32x4 w = *(const f32x4*)(wrow + j * 4);
        f32x4 q = *(const f32x4*)(qrow + j * 4);
        acc = fmaf(w[0], q[0], acc);
        acc = fmaf(w[1], q[1], acc);
        acc = fmaf(w[2], q[2], acc);
        acc = fmaf(w[3], q[3], acc);
    }
    qb[b * 256 + t] = acc + bq[t] + be[t];
}

// Main: e = ref @ We.T (bf16 MFMA), tanh(qb + e) . v  -> scores [B][G]
__global__ __launch_bounds__(512, 2) void attn_kernel(
    const float* __restrict__ ref, const float* __restrict__ We,
    const float* __restrict__ vvec, const float* __restrict__ qb,
    float* __restrict__ out)
{
    extern __shared__ char lds[];   // 131072 B: We as bf16 [256 rows][512 B], XOR-swizzled
    const int tid = threadIdx.x;

    // ---- stage We (f32 global -> bf16 LDS, swizzle byte ^= (row&7)<<4) ----
    // Each thread owns half a row: 128 f32 -> 256 B of bf16, 16 iters of
    // 8 floats -> one 16 B write at stride 16.
    {
        const int r = tid >> 1;       // row 0..255 (= output feature n)
        const int h = tid & 1;        // which half of the row
        const float* src = We + (size_t)r * 256 + h * 128;
        const uint32_t swz = (uint32_t)((r & 7) << 4);
#pragma unroll
        for (int i = 0; i < 16; ++i) {
            f32x4 w0 = *(const f32x4*)(src + i * 8);
            f32x4 w1 = *(const f32x4*)(src + i * 8 + 4);
            u32x4 p;
            p[0] = pack2_bf16(w0[0], w0[1]);
            p[1] = pack2_bf16(w0[2], w0[3]);
            p[2] = pack2_bf16(w1[0], w1[1]);
            p[3] = pack2_bf16(w1[2], w1[3]);
            const uint32_t cb = (uint32_t)(h * 256 + i * 16);
            *(u32x4*)(lds + r * 512 + (cb ^ swz)) = p;
        }
    }
    __syncthreads();

    const int lane = tid & 63;
    const int wid  = tid >> 6;
    const int l31  = lane & 31;
    const int lhi  = lane >> 5;           // k-group half

    const uint32_t bbase = (uint32_t)(l31 * 512);        // B-frag row base (n within tile)
    const uint32_t bswz  = (uint32_t)((l31 & 7) << 4);
    const int      bcol0 = lhi * 16;                     // byte offset of k-group

    const int gw = blockIdx.x * 8 + wid;
    const int nw = gridDim.x * 8;

    for (int tile = gw; tile < TOTAL_TILES; tile += nw) {
        const int b  = tile / NT_PER_B;
        const int mt = tile - b * NT_PER_B;
        const int g0 = mt * 32;
        int gr = g0 + l31;
        if (gr > NG - 1) gr = NG - 1;     // clamp tail tile (rows not written)
        const float* ap = ref + ((size_t)(b * NG + gr)) * 256 + lhi * 8;

        f32x16 acc[8] = {};

        // 3-deep A prefetch, NAMED registers only (no runtime-indexed arrays
        // -> no scratch spill; spills were the round-3 700us culprit).
        f32x4 a0l = *(const f32x4*)(ap + 0*16), a0h = *(const f32x4*)(ap + 0*16 + 4);
        f32x4 a1l = *(const f32x4*)(ap + 1*16), a1h = *(const f32x4*)(ap + 1*16 + 4);
        f32x4 a2l = *(const f32x4*)(ap + 2*16), a2h = *(const f32x4*)(ap + 2*16 + 4);

#pragma unroll
        for (int ks = 0; ks < 16; ++ks) {
            u32x4 aq;
            aq[0] = pack2_bf16(a0l[0], a0l[1]);
            aq[1] = pack2_bf16(a0l[2], a0l[3]);
            aq[2] = pack2_bf16(a0h[0], a0h[1]);
            aq[3] = pack2_bf16(a0h[2], a0h[3]);
            short8 afrag = __builtin_bit_cast(short8, aq);

            f32x4 fl = a2l, fh = a2h;
            if (ks < 13) {
                fl = *(const f32x4*)(ap + (ks + 3) * 16);
                fh = *(const f32x4*)(ap + (ks + 3) * 16 + 4);
            }

            const uint32_t cb = ((uint32_t)(ks * 32 + bcol0)) ^ bswz;
#pragma unroll
            for (int nt = 0; nt < 8; ++nt) {
                short8 bfrag = *(const short8*)(lds + bbase + nt * 16384 + cb);
                acc[nt] = __builtin_amdgcn_mfma_f32_32x32x16_bf16(afrag, bfrag, acc[nt], 0, 0, 0);
            }

            a0l = a1l; a0h = a1h;
            a1l = a2l; a1h = a2h;
            a2l = fl;  a2h = fh;
        }

        // ---- epilogue: tanh(acc + qb) . v, butterfly-reduce over 32 col-lanes ----
        // qb/v loads live only here (L1/L2-hot, coalesced) to keep main-loop
        // register pressure low.
        float sums[16];
#pragma unroll
        for (int r = 0; r < 16; ++r) sums[r] = 0.0f;
        const float* qrow = qb + b * 256;
#pragma unroll
        for (int nt = 0; nt < 8; ++nt) {
            const float qv = qrow[nt * 32 + l31];
            const float vv = vvec[nt * 32 + l31];
#pragma unroll
            for (int r = 0; r < 16; ++r) {
                sums[r] = fmaf(tanh_fast(acc[nt][r] + qv), vv, sums[r]);
            }
        }
#pragma unroll
        for (int r = 0; r < 16; ++r) {
            float s = sums[r];
            s += __shfl_xor(s, 1);
            s += __shfl_xor(s, 2);
            s += __shfl_xor(s, 4);
            s += __shfl_xor(s, 8);
            s += __shfl_xor(s, 16);
            sums[r] = s;
        }
        if (l31 == 0) {   // lanes 0 and 32 write 16 rows each
            float* orow = out + (size_t)b * NG;
#pragma unroll
            for (int r = 0; r < 16; ++r) {
                const int rr = (r & 3) + 8 * (r >> 2) + 4 * lhi;  // C/D row map (m74/m101)
                const int g = g0 + rr;
                if (g < NG) orow[g] = sums[r];
            }
        }
    }
}

extern "C" void kernel_launch(void* const* d_in, const int* in_sizes, int n_in,
                              void* d_out, int out_size, void* d_ws, size_t ws_size,
                              hipStream_t stream) {
    const float* query = (const float*)d_in[0];
    const float* ref   = (const float*)d_in[1];
    const float* Wq    = (const float*)d_in[2];
    const float* bq    = (const float*)d_in[3];
    const float* We    = (const float*)d_in[4];
    const float* be    = (const float*)d_in[5];
    const float* v     = (const float*)d_in[6];
    float* out = (float*)d_out;
    float* qb  = (float*)d_ws;   // 256*256 f32 = 256 KB scratch

    // Allow 128 KiB dynamic LDS. Unconditional (idempotent, non-stream,
    // capture-safe).
    (void)hipFuncSetAttribute((const void*)attn_kernel,
                              hipFuncAttributeMaxDynamicSharedMemorySize, 131072);

    qb_kernel<<<dim3(NB), dim3(256), 0, stream>>>(query, Wq, bq, be, qb);
    attn_kernel<<<dim3(256), dim3(512), 131072, stream>>>(ref, We, v, qb, out);
}